// Round 5
// baseline (14492.413 us; speedup 1.0000x reference)
//
#include <hip/hip_runtime.h>
#include <cmath>

#define NWG 256
#define NTHR 1024

static constexpr int kV = 32000;
static constexpr int kS = 1024;
static constexpr int kT = 512;

// dfcW partition per WG: 125 rows total; first 61 in LDS, last 64 in regs.
static constexpr int kLdsRows = 61;

// dynamic-shared layout (floats)
static constexpr int kOffH0  = kLdsRows * 512;          // 31232
static constexpr int kOffH1  = kOffH0 + 512;            // 31744
static constexpr int kOffG   = kOffH1 + 512;            // 32256
static constexpr int kOffPK  = kOffG + 16;              // 32272 (8B aligned)
static constexpr int kOffTok = kOffPK + 32;             // 32304
static constexpr int kOffB   = kOffTok + 1;             // 32305
static constexpr int kSmemFloats = kOffB + kLdsRows;    // 32366
static constexpr unsigned kSmemBytes = ((kSmemFloats * 4 + 255) / 256) * 256;

struct SeqParams {
  const int* x; const int* y;
  const float* emb;
  const float* eWih0; const float* eWhh0; const float* eb0;
  const float* eWih1; const float* eWhh1; const float* eb1;
  const float* efcW;  const float* efcb;
  const float* dWih0; const float* dWhh0; const float* db0;
  const float* dWih1; const float* dWhh1; const float* db1;
  const float* dfcW;  const float* dfcb;
  float* out;
  float* P0;                 // [1024][2048] staging (ws or d_out fallback)
  float* st;                 // state area in ws
  unsigned long long* cand;  // [256] tagged packed argmax candidates
  unsigned* arrive;          // 256 packed 4B flags
};

__device__ __forceinline__ float sigmf(float v) { return 1.0f / (1.0f + expf(-v)); }

__device__ __forceinline__ float g_ld(const float* p_) {
  return __hip_atomic_load(p_, __ATOMIC_RELAXED, __HIP_MEMORY_SCOPE_AGENT);
}
__device__ __forceinline__ void g_st(float* p_, float v) {
  __hip_atomic_store(p_, v, __ATOMIC_RELAXED, __HIP_MEMORY_SCOPE_AGENT);
}
__device__ __forceinline__ unsigned long long g_ld64(const unsigned long long* p_) {
  return __hip_atomic_load(p_, __ATOMIC_RELAXED, __HIP_MEMORY_SCOPE_AGENT);
}
__device__ __forceinline__ void g_st64(unsigned long long* p_, unsigned long long v) {
  __hip_atomic_store(p_, v, __ATOMIC_RELAXED, __HIP_MEMORY_SCOPE_AGENT);
}
__device__ __forceinline__ unsigned g_ldu(const unsigned* p_) {
  return __hip_atomic_load(p_, __ATOMIC_RELAXED, __HIP_MEMORY_SCOPE_AGENT);
}

__device__ __forceinline__ float dot4(float4 a, float4 b) {
  return a.x * b.x + a.y * b.y + a.z * b.z + a.w * b.w;
}
__device__ __forceinline__ float wred(float a) {
  a += __shfl_down(a, 32);
  a += __shfl_down(a, 16);
  a += __shfl_down(a, 8);
  a += __shfl_down(a, 4);
  a += __shfl_down(a, 2);
  a += __shfl_down(a, 1);
  return a;
}

// One-hop all-poll grid barrier: each WG stores its packed 4B flag; wave 0
// polls all 256 flags with 4 coalesced loads (16 cachelines). Entry
// __syncthreads drains each wave's vmcnt, so all sc1 data stores are
// LLC-visible before the flag store. Monotone >= check tolerates fast WGs
// publishing gen+1 while slow WGs still poll gen.
__device__ void grid_barrier(const SeqParams& p, unsigned gen) {
  __syncthreads();
  if (threadIdx.x == 0)
    __hip_atomic_store(&p.arrive[blockIdx.x], gen, __ATOMIC_RELAXED,
                       __HIP_MEMORY_SCOPE_AGENT);
  if (threadIdx.x < 64) {
    const int l = threadIdx.x;
    for (;;) {
      const unsigned m0 = g_ldu(&p.arrive[l]);
      const unsigned m1 = g_ldu(&p.arrive[l + 64]);
      const unsigned m2 = g_ldu(&p.arrive[l + 128]);
      const unsigned m3 = g_ldu(&p.arrive[l + 192]);
      const bool ok = (m0 >= gen) & (m1 >= gen) & (m2 >= gen) & (m3 >= gen);
      if (__all(ok)) break;
      __builtin_amdgcn_s_sleep(1);
    }
  }
  __syncthreads();
}

// Tagged candidate packing: key(32) | inv_row15(15) | tag(17).
// Same (key desc, row asc) ordering as before among equal tags.
__device__ __forceinline__ unsigned long long pack_cand(float a, int row,
                                                        unsigned tag) {
  const unsigned u = __float_as_uint(a);
  const unsigned key = u ^ (unsigned)(((int)u >> 31) | 0x80000000);
  return ((unsigned long long)key << 32) |
         ((unsigned long long)(0x7FFFu ^ (unsigned)row) << 17) |
         (unsigned long long)tag;
}

__global__ __launch_bounds__(NTHR, 4) void seq2seq_kernel(SeqParams p) {
  extern __shared__ float smem[];
  float* lds_w  = smem;                  // [61][512] dfcW rows (+8KB em alias)
  float* lds_h0 = smem + kOffH0;         // [512]
  float* lds_h1 = smem + kOffH1;         // [512]
  float* lds_g  = smem + kOffG;          // [16]
  unsigned long long* lds_pk =
      reinterpret_cast<unsigned long long*>(smem + kOffPK);  // [16]
  float* lds_tok = smem + kOffTok;       // [1]
  float* lds_b   = smem + kOffB;         // [61] dfcb for LDS rows

  const int w = blockIdx.x;
  const int tid = threadIdx.x;
  const int wave = tid >> 6, lane = tid & 63;
  unsigned gen = 0;

  // state layout (floats) in ws
  float* H0e = p.st;                 // [2][512]
  float* H1e = p.st + 1024;          // [2][512]
  float* H0d = p.st + 2048;          // [2][512]
  float* H1d = p.st + 3072;          // [2][512]

  // ============ Phase 0: P0 = emb[x] @ Wih0^T + b0 ; zero enc h ============
  {
    if (w == 0 && tid < 512) { g_st(&H0e[tid], 0.f); g_st(&H1e[tid], 0.f); }
    float* lds_em = lds_w;                  // 2048 floats, dead after GEMM
    const int t0  = (w & 127) * 8;          // 8 timesteps per WG
    const int row = (w >> 7) * 1024 + tid;  // 2 row-slices of 1024
    float4* emv = reinterpret_cast<float4*>(lds_em);
    if (tid < 512) {
      const int tl = tid >> 6, kq = tid & 63;
      const int tk = p.x[t0 + tl];
      emv[tid] = reinterpret_cast<const float4*>(p.emb)[(size_t)tk * 64 + kq];
    }
    __syncthreads();
    float acc[8];
    const float b = p.eb0[row];
#pragma unroll
    for (int t = 0; t < 8; ++t) acc[t] = b;
    for (int kc = 0; kc < 4; ++kc) {
      float4 wv[16];
      const float4* wr =
          reinterpret_cast<const float4*>(p.eWih0 + (size_t)row * 256) + kc * 16;
#pragma unroll
      for (int i = 0; i < 16; ++i) wv[i] = wr[i];
#pragma unroll
      for (int t = 0; t < 8; ++t) {
        const float4* ev =
            reinterpret_cast<const float4*>(lds_em + t * 256) + kc * 16;
        float a = acc[t];
#pragma unroll
        for (int i = 0; i < 16; ++i) a += dot4(wv[i], ev[i]);
        acc[t] = a;
      }
    }
#pragma unroll
    for (int t = 0; t < 8; ++t)
      g_st(&p.P0[(size_t)(t0 + t) * 2048 + row], acc[t]);
    __syncthreads();  // all lds_em reads done before weights overwrite it

    // ---- Load dfcW rows [w*125, w*125+61) into LDS (held all kernel) ----
    const float4* gw4 =
        reinterpret_cast<const float4*>(p.dfcW + (size_t)w * 125 * 512);
    float4* lw4 = reinterpret_cast<float4*>(lds_w);
    for (int i = tid; i < kLdsRows * 128; i += NTHR) lw4[i] = gw4[i];
    if (tid < kLdsRows) lds_b[tid] = p.dfcb[w * 125 + tid];
  }
  grid_barrier(p, ++gen);

  // ============ Encoder: pipelined L0(t=ph) || L1(t=ph-1) ==================
  float c0e = 0.f, c1e = 0.f;   // per-unit cell state, WG-private (registers)
  int row_l0 = 0;
  float pv_next = 0.f;
  if (w < 128) {
    row_l0 = (wave & 3) * 512 + w * 4 + (wave >> 2);
    if (lane == 0) pv_next = g_ld(&p.P0[row_l0]);  // prefetch P0[t=0]
  }

  for (int ph = 0; ph <= kS; ++ph) {
    if (w < 128) {
      if (ph < kS) {
        if (tid < 512) lds_h0[tid] = g_ld(&H0e[(ph & 1) * 512 + tid]);
        __syncthreads();
        const float pv = pv_next;
        if (lane == 0 && ph + 1 < kS)
          pv_next = g_ld(&p.P0[(size_t)(ph + 1) * 2048 + row_l0]);
        const float4* W4 =
            reinterpret_cast<const float4*>(p.eWhh0 + (size_t)row_l0 * 512);
        const float4* h4 = reinterpret_cast<const float4*>(lds_h0);
        float a = dot4(W4[lane * 2], h4[lane * 2]) +
                  dot4(W4[lane * 2 + 1], h4[lane * 2 + 1]);
        a = wred(a);
        if (lane == 0) lds_g[wave] = a + pv;  // pv includes b0
        __syncthreads();
        if (tid < 4) {
          const int u = w * 4 + tid;
          const float gi = lds_g[tid * 4 + 0];
          const float gf = lds_g[tid * 4 + 1];
          const float gg = lds_g[tid * 4 + 2];
          const float go = lds_g[tid * 4 + 3];
          const float c2 = sigmf(gf) * c0e + sigmf(gi) * tanhf(gg);
          c0e = c2;
          g_st(&H0e[((ph + 1) & 1) * 512 + u], sigmf(go) * tanhf(c2));
        }
      }
    } else {
      if (ph >= 1) {
        const int ww = w - 128;
        if (tid < 512) lds_h0[tid] = g_ld(&H0e[(ph & 1) * 512 + tid]);
        else lds_h1[tid - 512] = g_ld(&H1e[((ph - 1) & 1) * 512 + (tid - 512)]);
        __syncthreads();
        const int row = (wave & 3) * 512 + ww * 4 + (wave >> 2);
        const float4* Wa =
            reinterpret_cast<const float4*>(p.eWih1 + (size_t)row * 512);
        const float4* Wb =
            reinterpret_cast<const float4*>(p.eWhh1 + (size_t)row * 512);
        const float4* h4a = reinterpret_cast<const float4*>(lds_h0);
        const float4* h4b = reinterpret_cast<const float4*>(lds_h1);
        float a = (lane == 0) ? p.eb1[row] : 0.f;
        a += dot4(Wa[lane * 2], h4a[lane * 2]) +
             dot4(Wa[lane * 2 + 1], h4a[lane * 2 + 1]);
        a += dot4(Wb[lane * 2], h4b[lane * 2]) +
             dot4(Wb[lane * 2 + 1], h4b[lane * 2 + 1]);
        a = wred(a);
        if (lane == 0) lds_g[wave] = a;
        __syncthreads();
        if (tid < 4) {
          const int u = ww * 4 + tid;
          const float gi = lds_g[tid * 4 + 0];
          const float gf = lds_g[tid * 4 + 1];
          const float gg = lds_g[tid * 4 + 2];
          const float go = lds_g[tid * 4 + 3];
          const float c2 = sigmf(gf) * c1e + sigmf(gi) * tanhf(gg);
          c1e = c2;
          g_st(&H1e[(ph & 1) * 512 + u], sigmf(go) * tanhf(c2));
        }
      }
    }
    grid_barrier(p, ++gen);
  }

  // ============ z = relu(efcW @ h1_final + efcb); init decoder =============
  float c0d = 0.f, c1d = 0.f;
  {
    if (tid < 512) lds_h0[tid] = g_ld(&H1e[tid]);  // final h1 in buf 0
    __syncthreads();
    if (wave < 2) {
      const int u = w * 2 + wave;
      const float4* W4 =
          reinterpret_cast<const float4*>(p.efcW + (size_t)u * 512);
      const float4* h4 = reinterpret_cast<const float4*>(lds_h0);
      float a = dot4(W4[lane * 2], h4[lane * 2]) +
                dot4(W4[lane * 2 + 1], h4[lane * 2 + 1]);
      a = wred(a);
      if (lane == 0) lds_g[wave] = fmaxf(a + p.efcb[u], 0.f);
    }
    __syncthreads();
    if (tid < 2) {
      const int uu = w * 2 + tid;
      const float z = lds_g[tid];
      c0d = z; c1d = z;
      g_st(&H0d[uu], z);
      g_st(&H1d[uu], z);
    }
  }

  // ---- Load dfcW rows [w*125+61, w*125+125) into registers (decoder-only
  // live range; wave v owns rows w*125+61+v*4+{0..3}). 32 VGPR + 4 bias.
  float4 Ra0, Rb0, Ra1, Rb1, Ra2, Rb2, Ra3, Rb3;
  float bi0, bi1, bi2, bi3;
  {
    const int rb = w * 125 + kLdsRows + wave * 4;
#define LWR(i)                                                                \
  {                                                                           \
    const float4* q =                                                         \
        reinterpret_cast<const float4*>(p.dfcW + (size_t)(rb + i) * 512) +    \
        lane * 2;                                                             \
    Ra##i = q[0];                                                             \
    Rb##i = q[1];                                                             \
    bi##i = p.dfcb[rb + i];                                                   \
  }
    LWR(0) LWR(1) LWR(2) LWR(3)
#undef LWR
  }
  grid_barrier(p, ++gen);

  // ============ Decoder: 511 steps, 2 barriers + tagged-cand poll ==========
  for (int t = 0; t < kT - 1; ++t) {
    // ---- D0: (tagged token reduce by wave 15) || Whh0 @ h0 dots ----
    // H0d[(t)&1 ... slot (t+1)&1 math]: reads slot written at D0(t-1)/init,
    // visibility via the D0->D1 barrier of the previous step.
    {
      if (tid < 512) lds_h0[tid] = g_ld(&H0d[(t & 1) * 512 + tid]);
      if (wave == 15) {
        if (t == 0) {
          if (lane == 0) lds_tok[0] = (float)p.y[0];
        } else {
          const unsigned tagexp = (unsigned)t;
          unsigned long long k0, k1, k2, k3;
          for (;;) {
            k0 = g_ld64(&p.cand[lane]);
            k1 = g_ld64(&p.cand[lane + 64]);
            k2 = g_ld64(&p.cand[lane + 128]);
            k3 = g_ld64(&p.cand[lane + 192]);
            const bool ok = ((unsigned)(k0 & 0x1FFFF) == tagexp) &
                            ((unsigned)(k1 & 0x1FFFF) == tagexp) &
                            ((unsigned)(k2 & 0x1FFFF) == tagexp) &
                            ((unsigned)(k3 & 0x1FFFF) == tagexp);
            if (__all(ok)) break;
            __builtin_amdgcn_s_sleep(1);
          }
          unsigned long long pk = k0;
          if (k1 > pk) pk = k1;
          if (k2 > pk) pk = k2;
          if (k3 > pk) pk = k3;
#pragma unroll
          for (int off = 32; off >= 1; off >>= 1) {
            const unsigned long long o = __shfl_down(pk, off);
            if (o > pk) pk = o;
          }
          if (lane == 0)
            lds_tok[0] = (float)(0x7FFFu ^ (unsigned)((pk >> 17) & 0x7FFF));
        }
      }
      __syncthreads();
      if (wave < 8) {
        const int row = (wave & 3) * 512 + w * 2 + (wave >> 2);
        const float4* W4 =
            reinterpret_cast<const float4*>(p.dWhh0 + (size_t)row * 512);
        const float4* h4 = reinterpret_cast<const float4*>(lds_h0);
        float a = dot4(W4[lane * 2], h4[lane * 2]) +
                  dot4(W4[lane * 2 + 1], h4[lane * 2 + 1]);
        a = wred(a);
        if (lane == 0) lds_g[wave] = a;
      }
      __syncthreads();
      if (tid < 2) {
        const float tok = lds_tok[0];
        const int uu = w * 2 + tid;
        float gv[4];
#pragma unroll
        for (int g = 0; g < 4; ++g) {
          const int rg = g * 512 + uu;
          gv[g] = lds_g[tid * 4 + g] + p.dWih0[rg] * tok + p.db0[rg];
        }
        const float c2 = sigmf(gv[1]) * c0d + sigmf(gv[0]) * tanhf(gv[2]);
        c0d = c2;
        g_st(&H0d[((t + 1) & 1) * 512 + uu], sigmf(gv[3]) * tanhf(c2));
      }
    }
    grid_barrier(p, ++gen);
    // ---- D1: Wih1 @ h0_new + Whh1 @ h1_old ----
    {
      if (tid < 512) lds_h0[tid] = g_ld(&H0d[((t + 1) & 1) * 512 + tid]);
      else lds_h1[tid - 512] = g_ld(&H1d[(t & 1) * 512 + (tid - 512)]);
      __syncthreads();
      if (wave < 8) {
        const int row = (wave & 3) * 512 + w * 2 + (wave >> 2);
        const float4* Wa =
            reinterpret_cast<const float4*>(p.dWih1 + (size_t)row * 512);
        const float4* Wb =
            reinterpret_cast<const float4*>(p.dWhh1 + (size_t)row * 512);
        const float4* h4a = reinterpret_cast<const float4*>(lds_h0);
        const float4* h4b = reinterpret_cast<const float4*>(lds_h1);
        float a = (lane == 0) ? p.db1[row] : 0.f;
        a += dot4(Wa[lane * 2], h4a[lane * 2]) +
             dot4(Wa[lane * 2 + 1], h4a[lane * 2 + 1]);
        a += dot4(Wb[lane * 2], h4b[lane * 2]) +
             dot4(Wb[lane * 2 + 1], h4b[lane * 2 + 1]);
        a = wred(a);
        if (lane == 0) lds_g[wave] = a;
      }
      __syncthreads();
      if (tid < 2) {
        const int uu = w * 2 + tid;
        const float gi = lds_g[tid * 4 + 0];
        const float gf = lds_g[tid * 4 + 1];
        const float gg = lds_g[tid * 4 + 2];
        const float go = lds_g[tid * 4 + 3];
        const float c2 = sigmf(gf) * c1d + sigmf(gi) * tanhf(gg);
        c1d = c2;
        g_st(&H1d[((t + 1) & 1) * 512 + uu], sigmf(go) * tanhf(c2));
      }
    }
    grid_barrier(p, ++gen);
    // ---- FC: logits from LDS+register weights; store TAGGED candidate ----
    // No grid barrier after: consumers poll the tag (one hop, overlapped
    // with next step's D0 dots).
    {
      if (tid < 512) lds_h0[tid] = g_ld(&H1d[((t + 1) & 1) * 512 + tid]);
      __syncthreads();
      const float4* h4 = reinterpret_cast<const float4*>(lds_h0);
      const float4 ha = h4[lane * 2], hb = h4[lane * 2 + 1];
      float* orow = p.out + (size_t)(t + 1) * kV;
      const unsigned tagout = (unsigned)(t + 1);
      unsigned long long best = 0;
      // register rows
      const int rb = w * 125 + kLdsRows + wave * 4;
#define FCR(i)                                                                \
  {                                                                           \
    const int row = rb + i;                                                   \
    float a = (lane == 0) ? bi##i : 0.f;                                      \
    a += dot4(Ra##i, ha) + dot4(Rb##i, hb);                                   \
    a = wred(a);                                                              \
    if (lane == 0) {                                                          \
      orow[row] = a;                                                          \
      const unsigned long long pk2 = pack_cand(a, row, tagout);               \
      if (pk2 > best) best = pk2;                                             \
    }                                                                         \
  }
      FCR(0) FCR(1) FCR(2) FCR(3)
#undef FCR
      // LDS rows: wave v handles rr = v, v+16, v+32, v+48 (rr < 61)
      for (int rr = wave; rr < kLdsRows; rr += 16) {
        const int row = w * 125 + rr;
        const float4* lw = reinterpret_cast<const float4*>(lds_w + rr * 512);
        float a = (lane == 0) ? lds_b[rr] : 0.f;
        a += dot4(lw[lane * 2], ha) + dot4(lw[lane * 2 + 1], hb);
        a = wred(a);
        if (lane == 0) {
          orow[row] = a;
          const unsigned long long pk2 = pack_cand(a, row, tagout);
          if (pk2 > best) best = pk2;
        }
      }
      if (lane == 0) lds_pk[wave] = best;
      __syncthreads();
      if (tid == 0) {
        unsigned long long b2 = lds_pk[0];
#pragma unroll
        for (int k2 = 1; k2 < 16; ++k2)
          if (lds_pk[k2] > b2) b2 = lds_pk[k2];
        g_st64(&p.cand[w], b2);
      }
    }
    // (no grid barrier here)
  }

  // zero output row 0 (P0 scratch in d_out, if used, is dead by now)
  {
    const int idx = w * NTHR + tid;
    if (idx < kV) p.out[idx] = 0.f;
  }
}

extern "C" void kernel_launch(void* const* d_in, const int* in_sizes, int n_in,
                              void* d_out, int out_size, void* d_ws, size_t ws_size,
                              hipStream_t stream) {
  (void)in_sizes; (void)n_in; (void)out_size;
  SeqParams P;
  P.x     = (const int*)d_in[0];
  P.y     = (const int*)d_in[1];
  P.emb   = (const float*)d_in[2];
  P.eWih0 = (const float*)d_in[3];
  P.eWhh0 = (const float*)d_in[4];
  P.eb0   = (const float*)d_in[5];
  P.eWih1 = (const float*)d_in[6];
  P.eWhh1 = (const float*)d_in[7];
  P.eb1   = (const float*)d_in[8];
  P.efcW  = (const float*)d_in[9];
  P.efcb  = (const float*)d_in[10];
  P.dWih0 = (const float*)d_in[11];
  P.dWhh0 = (const float*)d_in[12];
  P.db0   = (const float*)d_in[13];
  P.dWih1 = (const float*)d_in[14];
  P.dWhh1 = (const float*)d_in[15];
  P.db1   = (const float*)d_in[16];
  P.dfcW  = (const float*)d_in[17];
  P.dfcb  = (const float*)d_in[18];
  P.out   = (float*)d_out;

  char* ws = (char*)d_ws;
  P.arrive = (unsigned*)ws;                       // 256 * 4B packed flags
  P.cand   = (unsigned long long*)(ws + 1024);    // 2KB tagged candidates
  P.st     = (float*)(ws + 4096);                 // 16KB H states
  const size_t p0_off  = 65536;
  const size_t p0_need = p0_off + 2048ull * 1024ull * sizeof(float);
  // P0 staging: prefer ws; fall back to d_out (region dead before decoder
  // overwrites it; row 0 re-zeroed at kernel end).
  P.P0 = (ws_size >= p0_need) ? (float*)(ws + p0_off) : (float*)d_out;

  // Allow >64KB dynamic LDS (idempotent, not a stream op; capture-safe).
  hipFuncSetAttribute(reinterpret_cast<const void*>(seq2seq_kernel),
                      hipFuncAttributeMaxDynamicSharedMemorySize,
                      (int)kSmemBytes);

  // Reset barrier flags + tagged candidates every call (replay-safe).
  hipMemsetAsync(d_ws, 0, 4096, stream);

  void* args[] = { &P };
  hipLaunchCooperativeKernel(reinterpret_cast<void*>(seq2seq_kernel),
                             dim3(NWG), dim3(NTHR), args, kSmemBytes, stream);
}

// Round 6
// 8265.224 us; speedup vs baseline: 1.7534x; 1.7534x over previous
//
#include <hip/hip_runtime.h>
#include <cmath>

#define NWG 256
#define NTHR 1024

static constexpr int kV = 32000;
static constexpr int kS = 1024;
static constexpr int kT = 512;

// dfcW partition per WG: 125 rows total; first 61 in LDS, last 64 in regs.
static constexpr int kLdsRows = 61;

// dynamic-shared layout (floats)
static constexpr int kOffH0  = kLdsRows * 512;          // 31232
static constexpr int kOffH1  = kOffH0 + 512;            // 31744
static constexpr int kOffG   = kOffH1 + 512;            // 32256
static constexpr int kOffPK  = kOffG + 16;              // 32272 (8B aligned)
static constexpr int kOffTok = kOffPK + 32;             // 32304
static constexpr int kOffB   = kOffTok + 1;             // 32305
static constexpr int kSmemFloats = kOffB + kLdsRows;    // 32366
static constexpr unsigned kSmemBytes = ((kSmemFloats * 4 + 255) / 256) * 256;

struct SeqParams {
  const int* x; const int* y;
  const float* emb;
  const float* eWih0; const float* eWhh0; const float* eb0;
  const float* eWih1; const float* eWhh1; const float* eb1;
  const float* efcW;  const float* efcb;
  const float* dWih0; const float* dWhh0; const float* db0;
  const float* dWih1; const float* dWhh1; const float* db1;
  const float* dfcW;  const float* dfcb;
  float* out;
  float* P0;                // [1024][2048] (ws or d_out fallback)
  unsigned long long* h0e;  // [1025][512] tagged pubs (append-only)
  unsigned long long* h1e;  // [1025][512]
  unsigned long long* h0d;  // [2][512] ring pubs
  unsigned long long* h1d;  // [2][512]
  unsigned long long* cand; // [256] tagged argmax candidates
  unsigned* arrive;         // 256 slots, 128B stride (one barrier)
  unsigned* go;             // 256 slots, 128B stride
};

__device__ __forceinline__ float sigmf(float v) { return 1.0f / (1.0f + expf(-v)); }

__device__ __forceinline__ float g_ld(const float* p_) {
  return __hip_atomic_load(p_, __ATOMIC_RELAXED, __HIP_MEMORY_SCOPE_AGENT);
}
__device__ __forceinline__ void g_st(float* p_, float v) {
  __hip_atomic_store(p_, v, __ATOMIC_RELAXED, __HIP_MEMORY_SCOPE_AGENT);
}
__device__ __forceinline__ unsigned long long g_ld64(const unsigned long long* p_) {
  return __hip_atomic_load(p_, __ATOMIC_RELAXED, __HIP_MEMORY_SCOPE_AGENT);
}
__device__ __forceinline__ void g_st64(unsigned long long* p_, unsigned long long v) {
  __hip_atomic_store(p_, v, __ATOMIC_RELAXED, __HIP_MEMORY_SCOPE_AGENT);
}

__device__ __forceinline__ float dot4(float4 a, float4 b) {
  return a.x * b.x + a.y * b.y + a.z * b.z + a.w * b.w;
}
__device__ __forceinline__ float wred(float a) {
  a += __shfl_down(a, 32);
  a += __shfl_down(a, 16);
  a += __shfl_down(a, 8);
  a += __shfl_down(a, 4);
  a += __shfl_down(a, 2);
  a += __shfl_down(a, 1);
  return a;
}

// Tagged publication: u64 = tag<<32 | f32 bits (atomic 8B store).
__device__ __forceinline__ void pub_write(unsigned long long* pub, int idx,
                                          unsigned tag, float v) {
  g_st64(&pub[idx],
         ((unsigned long long)tag << 32) | (unsigned long long)__float_as_uint(v));
}

// Poll-stage: one wave (wave8 in [0,8)) polls word idx=wave8*64+lane of a
// 512-word tagged pub vector until its tag matches, then stages the float
// into LDS. s_sleep(4) backoff limits LLC read-storm against the writers.
__device__ __forceinline__ void poll_stage(const unsigned long long* pub,
                                           unsigned tag, float* dst,
                                           int wave8, int lane) {
  const int idx = (wave8 << 6) | lane;
  unsigned long long x;
  for (;;) {
    x = g_ld64(&pub[idx]);
    if (__all((unsigned)(x >> 32) == tag)) break;
    __builtin_amdgcn_s_sleep(4);
  }
  dst[idx] = __uint_as_float((unsigned)x);
}

// Two-hop contention-free grid barrier (r4-proven; used ONCE after phase 0).
__device__ void grid_barrier(const SeqParams& p, unsigned gen) {
  __syncthreads();
  const int tid = threadIdx.x;
  if (blockIdx.x == 0) {
    if (tid > 0 && tid < 256) {
      while (__hip_atomic_load(&p.arrive[tid * 32], __ATOMIC_RELAXED,
                               __HIP_MEMORY_SCOPE_AGENT) < gen)
        __builtin_amdgcn_s_sleep(1);
    }
    __syncthreads();
    if (tid > 0 && tid < 256) {
      __hip_atomic_store(&p.go[tid * 32], gen, __ATOMIC_RELAXED,
                         __HIP_MEMORY_SCOPE_AGENT);
    }
  } else {
    if (tid == 0) {
      __hip_atomic_store(&p.arrive[blockIdx.x * 32], gen, __ATOMIC_RELAXED,
                         __HIP_MEMORY_SCOPE_AGENT);
      while (__hip_atomic_load(&p.go[blockIdx.x * 32], __ATOMIC_RELAXED,
                               __HIP_MEMORY_SCOPE_AGENT) < gen)
        __builtin_amdgcn_s_sleep(1);
    }
    __syncthreads();
  }
}

// Tagged candidate packing: key(32) | inv_row15(15) | tag(17).
__device__ __forceinline__ unsigned long long pack_cand(float a, int row,
                                                        unsigned tag) {
  const unsigned u = __float_as_uint(a);
  const unsigned key = u ^ (unsigned)(((int)u >> 31) | 0x80000000);
  return ((unsigned long long)key << 32) |
         ((unsigned long long)(0x7FFFu ^ (unsigned)row) << 17) |
         (unsigned long long)tag;
}

__global__ __launch_bounds__(NTHR, 4) void seq2seq_kernel(SeqParams p) {
  extern __shared__ float smem[];
  float* lds_w  = smem;                  // [61][512] dfcW rows (+8KB em alias)
  float* lds_h0 = smem + kOffH0;         // [512]
  float* lds_h1 = smem + kOffH1;         // [512]
  float* lds_g  = smem + kOffG;          // [16]
  unsigned long long* lds_pk =
      reinterpret_cast<unsigned long long*>(smem + kOffPK);  // [16]
  float* lds_tok = smem + kOffTok;       // [1]
  float* lds_b   = smem + kOffB;         // [61] dfcb for LDS rows

  const int w = blockIdx.x;
  const int tid = threadIdx.x;
  const int wave = tid >> 6, lane = tid & 63;

  // ============ Phase 0: P0 GEMM; epub[0] init; dfcW LDS load ============
  {
    float* lds_em = lds_w;                  // 2048 floats, dead after GEMM
    const int t0  = (w & 127) * 8;
    const int row = (w >> 7) * 1024 + tid;
    float4* emv = reinterpret_cast<float4*>(lds_em);
    if (tid < 512) {
      const int tl = tid >> 6, kq = tid & 63;
      const int tk = p.x[t0 + tl];
      emv[tid] = reinterpret_cast<const float4*>(p.emb)[(size_t)tk * 64 + kq];
    }
    __syncthreads();
    float acc[8];
    const float b = p.eb0[row];
#pragma unroll
    for (int t = 0; t < 8; ++t) acc[t] = b;
    for (int kc = 0; kc < 4; ++kc) {
      float4 wv[16];
      const float4* wr =
          reinterpret_cast<const float4*>(p.eWih0 + (size_t)row * 256) + kc * 16;
#pragma unroll
      for (int i = 0; i < 16; ++i) wv[i] = wr[i];
#pragma unroll
      for (int t = 0; t < 8; ++t) {
        const float4* ev =
            reinterpret_cast<const float4*>(lds_em + t * 256) + kc * 16;
        float a = acc[t];
#pragma unroll
        for (int i = 0; i < 16; ++i) a += dot4(wv[i], ev[i]);
        acc[t] = a;
      }
    }
#pragma unroll
    for (int t = 0; t < 8; ++t)
      g_st(&p.P0[(size_t)(t0 + t) * 2048 + row], acc[t]);
    // initial states, tag 1
    if (tid < 4) {
      if (w < 128) pub_write(p.h0e, w * 4 + tid, 1u, 0.f);
      else         pub_write(p.h1e, (w - 128) * 4 + tid, 1u, 0.f);
    }
    __syncthreads();  // all lds_em reads done before weights overwrite it

    const float4* gw4 =
        reinterpret_cast<const float4*>(p.dfcW + (size_t)w * 125 * 512);
    float4* lw4 = reinterpret_cast<float4*>(lds_w);
    for (int i = tid; i < kLdsRows * 128; i += NTHR) lw4[i] = gw4[i];
    if (tid < kLdsRows) lds_b[tid] = p.dfcb[w * 125 + tid];
  }
  grid_barrier(p, 1u);  // makes P0 + epub[0] globally visible

  // ============ Encoder: barrier-free dataflow ============================
  if (w < 128) {
    // L0 chain: poll h0e[i] (tag i+1) -> publish h0e[i+1] (tag i+2)
    const int row_l0 = (wave & 3) * 512 + w * 4 + (wave >> 2);
    float pv_next = 0.f;
    if (lane == 0) pv_next = g_ld(&p.P0[row_l0]);
    float c0e = 0.f;
    for (int i = 0; i < kS; ++i) {
      if (wave < 8)
        poll_stage(p.h0e + (size_t)i * 512, (unsigned)(i + 1), lds_h0, wave, lane);
      __syncthreads();
      const float pv = pv_next;
      if (lane == 0 && i + 1 < kS)
        pv_next = g_ld(&p.P0[(size_t)(i + 1) * 2048 + row_l0]);
      const float4* W4 =
          reinterpret_cast<const float4*>(p.eWhh0 + (size_t)row_l0 * 512);
      const float4* h4 = reinterpret_cast<const float4*>(lds_h0);
      float a = dot4(W4[lane * 2], h4[lane * 2]) +
                dot4(W4[lane * 2 + 1], h4[lane * 2 + 1]);
      a = wred(a);
      if (lane == 0) lds_g[wave] = a + pv;  // pv includes b0
      __syncthreads();
      if (tid < 4) {
        const float gi = lds_g[tid * 4 + 0];
        const float gf = lds_g[tid * 4 + 1];
        const float gg = lds_g[tid * 4 + 2];
        const float go = lds_g[tid * 4 + 3];
        const float c2 = sigmf(gf) * c0e + sigmf(gi) * tanhf(gg);
        c0e = c2;
        pub_write(p.h0e, (int)((size_t)(i + 1) * 512) + w * 4 + tid,
                  (unsigned)(i + 2), sigmf(go) * tanhf(c2));
      }
    }
  } else {
    // L1 chain: poll h0e[j+1] (tag j+2) + h1e[j] (tag j+1) -> pub h1e[j+1]
    const int ww = w - 128;
    const int row = (wave & 3) * 512 + ww * 4 + (wave >> 2);
    float c1e = 0.f;
    for (int j = 0; j < kS; ++j) {
      if (wave < 8)
        poll_stage(p.h0e + (size_t)(j + 1) * 512, (unsigned)(j + 2), lds_h0,
                   wave, lane);
      else
        poll_stage(p.h1e + (size_t)j * 512, (unsigned)(j + 1), lds_h1,
                   wave - 8, lane);
      __syncthreads();
      const float4* Wa =
          reinterpret_cast<const float4*>(p.eWih1 + (size_t)row * 512);
      const float4* Wb =
          reinterpret_cast<const float4*>(p.eWhh1 + (size_t)row * 512);
      const float4* h4a = reinterpret_cast<const float4*>(lds_h0);
      const float4* h4b = reinterpret_cast<const float4*>(lds_h1);
      float a = (lane == 0) ? p.eb1[row] : 0.f;
      a += dot4(Wa[lane * 2], h4a[lane * 2]) +
           dot4(Wa[lane * 2 + 1], h4a[lane * 2 + 1]);
      a += dot4(Wb[lane * 2], h4b[lane * 2]) +
           dot4(Wb[lane * 2 + 1], h4b[lane * 2 + 1]);
      a = wred(a);
      if (lane == 0) lds_g[wave] = a;
      __syncthreads();
      if (tid < 4) {
        const float gi = lds_g[tid * 4 + 0];
        const float gf = lds_g[tid * 4 + 1];
        const float gg = lds_g[tid * 4 + 2];
        const float go = lds_g[tid * 4 + 3];
        const float c2 = sigmf(gf) * c1e + sigmf(gi) * tanhf(gg);
        c1e = c2;
        pub_write(p.h1e, (int)((size_t)(j + 1) * 512) + ww * 4 + tid,
                  (unsigned)(j + 2), sigmf(go) * tanhf(c2));
      }
    }
  }

  // ============ z = relu(efcW @ h1_final + efcb); pub decoder state 0 =====
  float c0d = 0.f, c1d = 0.f;
  {
    if (wave < 8)
      poll_stage(p.h1e + (size_t)kS * 512, (unsigned)(kS + 1), lds_h0, wave, lane);
    __syncthreads();
    if (wave < 2) {
      const int u = w * 2 + wave;
      const float4* W4 =
          reinterpret_cast<const float4*>(p.efcW + (size_t)u * 512);
      const float4* h4 = reinterpret_cast<const float4*>(lds_h0);
      float a = dot4(W4[lane * 2], h4[lane * 2]) +
                dot4(W4[lane * 2 + 1], h4[lane * 2 + 1]);
      a = wred(a);
      if (lane == 0) lds_g[wave] = fmaxf(a + p.efcb[u], 0.f);
    }
    __syncthreads();
    if (tid < 2) {
      const int uu = w * 2 + tid;
      const float z = lds_g[tid];
      c0d = z; c1d = z;
      pub_write(p.h0d, uu, 1u, z);  // slot 0, tag 1
      pub_write(p.h1d, uu, 1u, z);
    }
  }

  // ---- dfcW register rows (wave v owns rows w*125+61+v*4+{0..3}) ----
  float4 Ra0, Rb0, Ra1, Rb1, Ra2, Rb2, Ra3, Rb3;
  float bi0, bi1, bi2, bi3;
  {
    const int rb = w * 125 + kLdsRows + wave * 4;
#define LWR(i)                                                                \
  {                                                                           \
    const float4* q =                                                         \
        reinterpret_cast<const float4*>(p.dfcW + (size_t)(rb + i) * 512) +    \
        lane * 2;                                                             \
    Ra##i = q[0];                                                             \
    Rb##i = q[1];                                                             \
    bi##i = p.dfcb[rb + i];                                                   \
  }
    LWR(0) LWR(1) LWR(2) LWR(3)
#undef LWR
  }

  // ============ Decoder: barrier-free, 3 one-hop waits per step ===========
  for (int t = 0; t < kT - 1; ++t) {
    // ---- D0: poll h0d slot t&1 (tag t+1); wave15 resolves token ----
    {
      if (wave < 8) {
        poll_stage(p.h0d + (t & 1) * 512, (unsigned)(t + 1), lds_h0, wave, lane);
      } else if (wave == 15) {
        if (t == 0) {
          if (lane == 0) lds_tok[0] = (float)p.y[0];
        } else {
          const unsigned tagexp = (unsigned)t;
          unsigned long long k0, k1, k2, k3;
          for (;;) {
            k0 = g_ld64(&p.cand[lane]);
            k1 = g_ld64(&p.cand[lane + 64]);
            k2 = g_ld64(&p.cand[lane + 128]);
            k3 = g_ld64(&p.cand[lane + 192]);
            const bool ok = ((unsigned)(k0 & 0x1FFFF) == tagexp) &
                            ((unsigned)(k1 & 0x1FFFF) == tagexp) &
                            ((unsigned)(k2 & 0x1FFFF) == tagexp) &
                            ((unsigned)(k3 & 0x1FFFF) == tagexp);
            if (__all(ok)) break;
            __builtin_amdgcn_s_sleep(1);
          }
          unsigned long long pk = k0;
          if (k1 > pk) pk = k1;
          if (k2 > pk) pk = k2;
          if (k3 > pk) pk = k3;
#pragma unroll
          for (int off = 32; off >= 1; off >>= 1) {
            const unsigned long long o = __shfl_down(pk, off);
            if (o > pk) pk = o;
          }
          if (lane == 0)
            lds_tok[0] = (float)(0x7FFFu ^ (unsigned)((pk >> 17) & 0x7FFF));
        }
      }
      __syncthreads();
      if (wave < 8) {
        const int row = (wave & 3) * 512 + w * 2 + (wave >> 2);
        const float4* W4 =
            reinterpret_cast<const float4*>(p.dWhh0 + (size_t)row * 512);
        const float4* h4 = reinterpret_cast<const float4*>(lds_h0);
        float a = dot4(W4[lane * 2], h4[lane * 2]) +
                  dot4(W4[lane * 2 + 1], h4[lane * 2 + 1]);
        a = wred(a);
        if (lane == 0) lds_g[wave] = a;
      }
      __syncthreads();
      if (tid < 2) {
        const float tok = lds_tok[0];
        const int uu = w * 2 + tid;
        float gv[4];
#pragma unroll
        for (int g = 0; g < 4; ++g) {
          const int rg = g * 512 + uu;
          gv[g] = lds_g[tid * 4 + g] + p.dWih0[rg] * tok + p.db0[rg];
        }
        const float c2 = sigmf(gv[1]) * c0d + sigmf(gv[0]) * tanhf(gv[2]);
        c0d = c2;
        pub_write(p.h0d, ((t + 1) & 1) * 512 + uu, (unsigned)(t + 2),
                  sigmf(gv[3]) * tanhf(c2));
      }
    }
    // ---- D1: poll h0d slot (t+1)&1 (tag t+2) + h1d slot t&1 (tag t+1) ----
    {
      if (wave < 8)
        poll_stage(p.h0d + ((t + 1) & 1) * 512, (unsigned)(t + 2), lds_h0,
                   wave, lane);
      else
        poll_stage(p.h1d + (t & 1) * 512, (unsigned)(t + 1), lds_h1,
                   wave - 8, lane);
      __syncthreads();
      if (wave < 8) {
        const int row = (wave & 3) * 512 + w * 2 + (wave >> 2);
        const float4* Wa =
            reinterpret_cast<const float4*>(p.dWih1 + (size_t)row * 512);
        const float4* Wb =
            reinterpret_cast<const float4*>(p.dWhh1 + (size_t)row * 512);
        const float4* h4a = reinterpret_cast<const float4*>(lds_h0);
        const float4* h4b = reinterpret_cast<const float4*>(lds_h1);
        float a = (lane == 0) ? p.db1[row] : 0.f;
        a += dot4(Wa[lane * 2], h4a[lane * 2]) +
             dot4(Wa[lane * 2 + 1], h4a[lane * 2 + 1]);
        a += dot4(Wb[lane * 2], h4b[lane * 2]) +
             dot4(Wb[lane * 2 + 1], h4b[lane * 2 + 1]);
        a = wred(a);
        if (lane == 0) lds_g[wave] = a;
      }
      __syncthreads();
      if (tid < 2) {
        const int uu = w * 2 + tid;
        const float gi = lds_g[tid * 4 + 0];
        const float gf = lds_g[tid * 4 + 1];
        const float gg = lds_g[tid * 4 + 2];
        const float go = lds_g[tid * 4 + 3];
        const float c2 = sigmf(gf) * c1d + sigmf(gi) * tanhf(gg);
        c1d = c2;
        pub_write(p.h1d, ((t + 1) & 1) * 512 + uu, (unsigned)(t + 2),
                  sigmf(go) * tanhf(c2));
      }
    }
    // ---- FC: poll h1d slot (t+1)&1 (tag t+2); logits + tagged candidate ----
    {
      if (wave < 8)
        poll_stage(p.h1d + ((t + 1) & 1) * 512, (unsigned)(t + 2), lds_h0,
                   wave, lane);
      __syncthreads();
      const float4* h4 = reinterpret_cast<const float4*>(lds_h0);
      const float4 ha = h4[lane * 2], hb = h4[lane * 2 + 1];
      float* orow = p.out + (size_t)(t + 1) * kV;
      const unsigned tagout = (unsigned)(t + 1);
      unsigned long long best = 0;
      const int rb = w * 125 + kLdsRows + wave * 4;
#define FCR(i)                                                                \
  {                                                                           \
    const int row = rb + i;                                                   \
    float a = (lane == 0) ? bi##i : 0.f;                                      \
    a += dot4(Ra##i, ha) + dot4(Rb##i, hb);                                   \
    a = wred(a);                                                              \
    if (lane == 0) {                                                          \
      orow[row] = a;                                                          \
      const unsigned long long pk2 = pack_cand(a, row, tagout);               \
      if (pk2 > best) best = pk2;                                             \
    }                                                                         \
  }
      FCR(0) FCR(1) FCR(2) FCR(3)
#undef FCR
      for (int rr = wave; rr < kLdsRows; rr += 16) {
        const int row = w * 125 + rr;
        const float4* lw = reinterpret_cast<const float4*>(lds_w + rr * 512);
        float a = (lane == 0) ? lds_b[rr] : 0.f;
        a += dot4(lw[lane * 2], ha) + dot4(lw[lane * 2 + 1], hb);
        a = wred(a);
        if (lane == 0) {
          orow[row] = a;
          const unsigned long long pk2 = pack_cand(a, row, tagout);
          if (pk2 > best) best = pk2;
        }
      }
      if (lane == 0) lds_pk[wave] = best;
      __syncthreads();
      if (tid == 0) {
        unsigned long long b2 = lds_pk[0];
#pragma unroll
        for (int k2 = 1; k2 < 16; ++k2)
          if (lds_pk[k2] > b2) b2 = lds_pk[k2];
        g_st64(&p.cand[w], b2);
      }
    }
  }

  // zero output row 0 (P0/epub scratch in d_out, if used, is dead by now)
  {
    const int idx = w * NTHR + tid;
    if (idx < kV) p.out[idx] = 0.f;
  }
}

extern "C" void kernel_launch(void* const* d_in, const int* in_sizes, int n_in,
                              void* d_out, int out_size, void* d_ws, size_t ws_size,
                              hipStream_t stream) {
  (void)in_sizes; (void)n_in; (void)out_size;
  SeqParams P;
  P.x     = (const int*)d_in[0];
  P.y     = (const int*)d_in[1];
  P.emb   = (const float*)d_in[2];
  P.eWih0 = (const float*)d_in[3];
  P.eWhh0 = (const float*)d_in[4];
  P.eb0   = (const float*)d_in[5];
  P.eWih1 = (const float*)d_in[6];
  P.eWhh1 = (const float*)d_in[7];
  P.eb1   = (const float*)d_in[8];
  P.efcW  = (const float*)d_in[9];
  P.efcb  = (const float*)d_in[10];
  P.dWih0 = (const float*)d_in[11];
  P.dWhh0 = (const float*)d_in[12];
  P.db0   = (const float*)d_in[13];
  P.dWih1 = (const float*)d_in[14];
  P.dWhh1 = (const float*)d_in[15];
  P.db1   = (const float*)d_in[16];
  P.dfcW  = (const float*)d_in[17];
  P.dfcb  = (const float*)d_in[18];
  P.out   = (float*)d_out;

  char* ws = (char*)d_ws;
  P.arrive = (unsigned*)ws;                           // 32KB
  P.go     = (unsigned*)(ws + 32768);                 // 32KB
  P.cand   = (unsigned long long*)(ws + 65536);       // 2KB
  P.h0d    = (unsigned long long*)(ws + 67584);       // 8KB
  P.h1d    = (unsigned long long*)(ws + 75776);       // 8KB -> ends 83968

  const size_t kP0B  = 8388608ull;                    // 2048*1024*4
  const size_t kEpB  = 4198400ull;                    // 1025*512*8
  const size_t bigo  = 131072ull;
  if (ws_size >= bigo + kP0B + 2 * kEpB) {
    P.P0  = (float*)(ws + bigo);
    P.h0e = (unsigned long long*)(ws + bigo + kP0B);
    P.h1e = (unsigned long long*)(ws + bigo + kP0B + kEpB);
  } else {
    // d_out fallback: bytes [0, 16.8MB) = rows 0..~131, all dead before the
    // decoder's FC writes them (FC(t) writes row t+1, and any FC requires all
    // WGs to have finished the encoder via the cand/pub dependence chain).
    char* ob = (char*)d_out;
    P.P0  = (float*)ob;
    P.h0e = (unsigned long long*)(ob + kP0B);
    P.h1e = (unsigned long long*)(ob + kP0B + kEpB);
  }

  // Allow >64KB dynamic LDS (idempotent; capture-safe).
  hipFuncSetAttribute(reinterpret_cast<const void*>(seq2seq_kernel),
                      hipFuncAttributeMaxDynamicSharedMemorySize,
                      (int)kSmemBytes);

  // Reset barrier flags + cand + decoder ring pubs every call (replay-safe;
  // all poll tags are >=1 so zeroed words never satisfy a poll).
  hipMemsetAsync(d_ws, 0, 86016, stream);

  void* args[] = { &P };
  hipLaunchCooperativeKernel(reinterpret_cast<void*>(seq2seq_kernel),
                             dim3(NWG), dim3(NTHR), args, kSmemBytes, stream);
}

// Round 7
// 8253.200 us; speedup vs baseline: 1.7560x; 1.0015x over previous
//
#include <hip/hip_runtime.h>
#include <cmath>

#define NWG 256
#define NTHR 1024

static constexpr int kV = 32000;
static constexpr int kS = 1024;
static constexpr int kT = 512;

// dfcW partition per WG: 125 rows total; first 61 in LDS, last 64 in regs.
static constexpr int kLdsRows = 61;

// dynamic-shared layout (floats)
static constexpr int kOffH0  = kLdsRows * 512;          // 31232
static constexpr int kOffH1  = kOffH0 + 512;            // 31744
static constexpr int kOffG   = kOffH1 + 512;            // 32256
static constexpr int kOffPK  = kOffG + 16;              // 32272 (8B aligned)
static constexpr int kOffTok = kOffPK + 32;             // 32304
static constexpr int kOffB   = kOffTok + 1;             // 32305
static constexpr int kSmemFloats = kOffB + kLdsRows;    // 32366
static constexpr unsigned kSmemBytes = ((kSmemFloats * 4 + 255) / 256) * 256;

struct SeqParams {
  const int* x; const int* y;
  const float* emb;
  const float* eWih0; const float* eWhh0; const float* eb0;
  const float* eWih1; const float* eWhh1; const float* eb1;
  const float* efcW;  const float* efcb;
  const float* dWih0; const float* dWhh0; const float* db0;
  const float* dWih1; const float* dWhh1; const float* db1;
  const float* dfcW;  const float* dfcb;
  float* out;
  float* P0;                // [1024][2048] (ws or d_out fallback)
  unsigned long long* h0e;  // [1025][512] tagged pubs (append-only)
  unsigned long long* h1e;  // [1025][512]
  unsigned long long* h0d;  // [2][512] ring pubs
  unsigned long long* h1d;  // [2][512]
  unsigned long long* cand; // [256] tagged argmax candidates
  unsigned* arrive;         // 256 slots, 128B stride (one barrier)
  unsigned* go;             // 256 slots, 128B stride
};

__device__ __forceinline__ float sigmf(float v) { return 1.0f / (1.0f + expf(-v)); }

__device__ __forceinline__ float g_ld(const float* p_) {
  return __hip_atomic_load(p_, __ATOMIC_RELAXED, __HIP_MEMORY_SCOPE_AGENT);
}
__device__ __forceinline__ void g_st(float* p_, float v) {
  __hip_atomic_store(p_, v, __ATOMIC_RELAXED, __HIP_MEMORY_SCOPE_AGENT);
}
__device__ __forceinline__ unsigned long long g_ld64(const unsigned long long* p_) {
  return __hip_atomic_load(p_, __ATOMIC_RELAXED, __HIP_MEMORY_SCOPE_AGENT);
}
__device__ __forceinline__ void g_st64(unsigned long long* p_, unsigned long long v) {
  __hip_atomic_store(p_, v, __ATOMIC_RELAXED, __HIP_MEMORY_SCOPE_AGENT);
}

__device__ __forceinline__ float dot4(float4 a, float4 b) {
  return a.x * b.x + a.y * b.y + a.z * b.z + a.w * b.w;
}
__device__ __forceinline__ float wred(float a) {
  a += __shfl_down(a, 32);
  a += __shfl_down(a, 16);
  a += __shfl_down(a, 8);
  a += __shfl_down(a, 4);
  a += __shfl_down(a, 2);
  a += __shfl_down(a, 1);
  return a;
}

// Tagged publication: u64 = tag<<32 | f32 bits (atomic 8B store).
__device__ __forceinline__ void pub_write(unsigned long long* pub, int idx,
                                          unsigned tag, float v) {
  g_st64(&pub[idx],
         ((unsigned long long)tag << 32) | (unsigned long long)__float_as_uint(v));
}

// Poll-stage: one wave (wave8 in [0,8)) polls word idx=wave8*64+lane of a
// 512-word tagged pub vector until its tag matches, then stages the float
// into LDS. s_sleep(4) backoff limits LLC read-storm against the writers.
__device__ __forceinline__ void poll_stage(const unsigned long long* pub,
                                           unsigned tag, float* dst,
                                           int wave8, int lane) {
  const int idx = (wave8 << 6) | lane;
  unsigned long long x;
  for (;;) {
    x = g_ld64(&pub[idx]);
    if (__all((unsigned)(x >> 32) == tag)) break;
    __builtin_amdgcn_s_sleep(4);
  }
  dst[idx] = __uint_as_float((unsigned)x);
}

// Two-hop contention-free grid barrier (r4-proven; used ONCE after phase 0).
__device__ void grid_barrier(const SeqParams& p, unsigned gen) {
  __syncthreads();
  const int tid = threadIdx.x;
  if (blockIdx.x == 0) {
    if (tid > 0 && tid < 256) {
      while (__hip_atomic_load(&p.arrive[tid * 32], __ATOMIC_RELAXED,
                               __HIP_MEMORY_SCOPE_AGENT) < gen)
        __builtin_amdgcn_s_sleep(1);
    }
    __syncthreads();
    if (tid > 0 && tid < 256) {
      __hip_atomic_store(&p.go[tid * 32], gen, __ATOMIC_RELAXED,
                         __HIP_MEMORY_SCOPE_AGENT);
    }
  } else {
    if (tid == 0) {
      __hip_atomic_store(&p.arrive[blockIdx.x * 32], gen, __ATOMIC_RELAXED,
                         __HIP_MEMORY_SCOPE_AGENT);
      while (__hip_atomic_load(&p.go[blockIdx.x * 32], __ATOMIC_RELAXED,
                               __HIP_MEMORY_SCOPE_AGENT) < gen)
        __builtin_amdgcn_s_sleep(1);
    }
    __syncthreads();
  }
}

// Tagged candidate packing: key(32) | inv_row15(15) | tag(17).
__device__ __forceinline__ unsigned long long pack_cand(float a, int row,
                                                        unsigned tag) {
  const unsigned u = __float_as_uint(a);
  const unsigned key = u ^ (unsigned)(((int)u >> 31) | 0x80000000);
  return ((unsigned long long)key << 32) |
         ((unsigned long long)(0x7FFFu ^ (unsigned)row) << 17) |
         (unsigned long long)tag;
}

__global__ __launch_bounds__(NTHR, 4) void seq2seq_kernel(SeqParams p) {
  extern __shared__ float smem[];
  float* lds_w  = smem;                  // [61][512] dfcW rows (+8KB em alias)
  float* lds_h0 = smem + kOffH0;         // [512]
  float* lds_h1 = smem + kOffH1;         // [512]
  float* lds_g  = smem + kOffG;          // [16]
  unsigned long long* lds_pk =
      reinterpret_cast<unsigned long long*>(smem + kOffPK);  // [16]
  float* lds_tok = smem + kOffTok;       // [1]
  float* lds_b   = smem + kOffB;         // [61] dfcb for LDS rows

  const int w = blockIdx.x;
  const int tid = threadIdx.x;
  const int wave = tid >> 6, lane = tid & 63;

  // ============ Phase 0: P0 GEMM; epub[0] init; dfcW LDS load ============
  {
    float* lds_em = lds_w;                  // 2048 floats, dead after GEMM
    const int t0  = (w & 127) * 8;
    const int row = (w >> 7) * 1024 + tid;
    float4* emv = reinterpret_cast<float4*>(lds_em);
    if (tid < 512) {
      const int tl = tid >> 6, kq = tid & 63;
      const int tk = p.x[t0 + tl];
      emv[tid] = reinterpret_cast<const float4*>(p.emb)[(size_t)tk * 64 + kq];
    }
    __syncthreads();
    float acc[8];
    const float b = p.eb0[row];
#pragma unroll
    for (int t = 0; t < 8; ++t) acc[t] = b;
    for (int kc = 0; kc < 4; ++kc) {
      float4 wv[16];
      const float4* wr =
          reinterpret_cast<const float4*>(p.eWih0 + (size_t)row * 256) + kc * 16;
#pragma unroll
      for (int i = 0; i < 16; ++i) wv[i] = wr[i];
#pragma unroll
      for (int t = 0; t < 8; ++t) {
        const float4* ev =
            reinterpret_cast<const float4*>(lds_em + t * 256) + kc * 16;
        float a = acc[t];
#pragma unroll
        for (int i = 0; i < 16; ++i) a += dot4(wv[i], ev[i]);
        acc[t] = a;
      }
    }
#pragma unroll
    for (int t = 0; t < 8; ++t)
      g_st(&p.P0[(size_t)(t0 + t) * 2048 + row], acc[t]);
    // initial states, tag 1
    if (tid < 4) {
      if (w < 128) pub_write(p.h0e, w * 4 + tid, 1u, 0.f);
      else         pub_write(p.h1e, (w - 128) * 4 + tid, 1u, 0.f);
    }
    __syncthreads();  // all lds_em reads done before weights overwrite it

    const float4* gw4 =
        reinterpret_cast<const float4*>(p.dfcW + (size_t)w * 125 * 512);
    float4* lw4 = reinterpret_cast<float4*>(lds_w);
    for (int i = tid; i < kLdsRows * 128; i += NTHR) lw4[i] = gw4[i];
    if (tid < kLdsRows) lds_b[tid] = p.dfcb[w * 125 + tid];
  }
  grid_barrier(p, 1u);  // makes P0 + epub[0] globally visible

  // ============ Encoder: barrier-free dataflow ============================
  if (w < 128) {
    // L0 chain: poll h0e[i] (tag i+1) -> publish h0e[i+1] (tag i+2)
    const int row_l0 = (wave & 3) * 512 + w * 4 + (wave >> 2);
    float pv_next = 0.f;
    if (lane == 0) pv_next = g_ld(&p.P0[row_l0]);
    float c0e = 0.f;
    for (int i = 0; i < kS; ++i) {
      if (wave < 8)
        poll_stage(p.h0e + (size_t)i * 512, (unsigned)(i + 1), lds_h0, wave, lane);
      __syncthreads();
      const float pv = pv_next;
      if (lane == 0 && i + 1 < kS)
        pv_next = g_ld(&p.P0[(size_t)(i + 1) * 2048 + row_l0]);
      const float4* W4 =
          reinterpret_cast<const float4*>(p.eWhh0 + (size_t)row_l0 * 512);
      const float4* h4 = reinterpret_cast<const float4*>(lds_h0);
      float a = dot4(W4[lane * 2], h4[lane * 2]) +
                dot4(W4[lane * 2 + 1], h4[lane * 2 + 1]);
      a = wred(a);
      if (lane == 0) lds_g[wave] = a + pv;  // pv includes b0
      __syncthreads();
      if (tid < 4) {
        const float gi = lds_g[tid * 4 + 0];
        const float gf = lds_g[tid * 4 + 1];
        const float gg = lds_g[tid * 4 + 2];
        const float go = lds_g[tid * 4 + 3];
        const float c2 = sigmf(gf) * c0e + sigmf(gi) * tanhf(gg);
        c0e = c2;
        pub_write(p.h0e, (int)((size_t)(i + 1) * 512) + w * 4 + tid,
                  (unsigned)(i + 2), sigmf(go) * tanhf(c2));
      }
    }
  } else {
    // L1 chain: poll h0e[j+1] (tag j+2) + h1e[j] (tag j+1) -> pub h1e[j+1]
    const int ww = w - 128;
    const int row = (wave & 3) * 512 + ww * 4 + (wave >> 2);
    float c1e = 0.f;
    for (int j = 0; j < kS; ++j) {
      if (wave < 8)
        poll_stage(p.h0e + (size_t)(j + 1) * 512, (unsigned)(j + 2), lds_h0,
                   wave, lane);
      else
        poll_stage(p.h1e + (size_t)j * 512, (unsigned)(j + 1), lds_h1,
                   wave - 8, lane);
      __syncthreads();
      const float4* Wa =
          reinterpret_cast<const float4*>(p.eWih1 + (size_t)row * 512);
      const float4* Wb =
          reinterpret_cast<const float4*>(p.eWhh1 + (size_t)row * 512);
      const float4* h4a = reinterpret_cast<const float4*>(lds_h0);
      const float4* h4b = reinterpret_cast<const float4*>(lds_h1);
      float a = (lane == 0) ? p.eb1[row] : 0.f;
      a += dot4(Wa[lane * 2], h4a[lane * 2]) +
           dot4(Wa[lane * 2 + 1], h4a[lane * 2 + 1]);
      a += dot4(Wb[lane * 2], h4b[lane * 2]) +
           dot4(Wb[lane * 2 + 1], h4b[lane * 2 + 1]);
      a = wred(a);
      if (lane == 0) lds_g[wave] = a;
      __syncthreads();
      if (tid < 4) {
        const float gi = lds_g[tid * 4 + 0];
        const float gf = lds_g[tid * 4 + 1];
        const float gg = lds_g[tid * 4 + 2];
        const float go = lds_g[tid * 4 + 3];
        const float c2 = sigmf(gf) * c1e + sigmf(gi) * tanhf(gg);
        c1e = c2;
        pub_write(p.h1e, (int)((size_t)(j + 1) * 512) + ww * 4 + tid,
                  (unsigned)(j + 2), sigmf(go) * tanhf(c2));
      }
    }
  }

  // ============ z = relu(efcW @ h1_final + efcb); pub decoder state 0 =====
  float c0d = 0.f, c1d = 0.f;
  {
    if (wave < 8)
      poll_stage(p.h1e + (size_t)kS * 512, (unsigned)(kS + 1), lds_h0, wave, lane);
    __syncthreads();
    if (wave < 2) {
      const int u = w * 2 + wave;
      const float4* W4 =
          reinterpret_cast<const float4*>(p.efcW + (size_t)u * 512);
      const float4* h4 = reinterpret_cast<const float4*>(lds_h0);
      float a = dot4(W4[lane * 2], h4[lane * 2]) +
                dot4(W4[lane * 2 + 1], h4[lane * 2 + 1]);
      a = wred(a);
      if (lane == 0) lds_g[wave] = fmaxf(a + p.efcb[u], 0.f);
    }
    __syncthreads();
    if (tid < 2) {
      const int uu = w * 2 + tid;
      const float z = lds_g[tid];
      c0d = z; c1d = z;
      pub_write(p.h0d, uu, 1u, z);  // slot 0, tag 1
      pub_write(p.h1d, uu, 1u, z);
    }
  }

  // ---- dfcW register rows (wave v owns rows w*125+61+v*4+{0..3}) ----
  float4 Ra0, Rb0, Ra1, Rb1, Ra2, Rb2, Ra3, Rb3;
  float bi0, bi1, bi2, bi3;
  {
    const int rb = w * 125 + kLdsRows + wave * 4;
#define LWR(i)                                                                \
  {                                                                           \
    const float4* q =                                                         \
        reinterpret_cast<const float4*>(p.dfcW + (size_t)(rb + i) * 512) +    \
        lane * 2;                                                             \
    Ra##i = q[0];                                                             \
    Rb##i = q[1];                                                             \
    bi##i = p.dfcb[rb + i];                                                   \
  }
    LWR(0) LWR(1) LWR(2) LWR(3)
#undef LWR
  }

  // ============ Decoder: barrier-free, 3 one-hop waits per step ===========
  for (int t = 0; t < kT - 1; ++t) {
    // ---- D0: poll h0d slot t&1 (tag t+1); wave15 resolves token ----
    {
      if (wave < 8) {
        poll_stage(p.h0d + (t & 1) * 512, (unsigned)(t + 1), lds_h0, wave, lane);
      } else if (wave == 15) {
        if (t == 0) {
          if (lane == 0) lds_tok[0] = (float)p.y[0];
        } else {
          const unsigned tagexp = (unsigned)t;
          unsigned long long k0, k1, k2, k3;
          for (;;) {
            k0 = g_ld64(&p.cand[lane]);
            k1 = g_ld64(&p.cand[lane + 64]);
            k2 = g_ld64(&p.cand[lane + 128]);
            k3 = g_ld64(&p.cand[lane + 192]);
            const bool ok = ((unsigned)(k0 & 0x1FFFF) == tagexp) &
                            ((unsigned)(k1 & 0x1FFFF) == tagexp) &
                            ((unsigned)(k2 & 0x1FFFF) == tagexp) &
                            ((unsigned)(k3 & 0x1FFFF) == tagexp);
            if (__all(ok)) break;
            __builtin_amdgcn_s_sleep(1);
          }
          unsigned long long pk = k0;
          if (k1 > pk) pk = k1;
          if (k2 > pk) pk = k2;
          if (k3 > pk) pk = k3;
#pragma unroll
          for (int off = 32; off >= 1; off >>= 1) {
            const unsigned long long o = __shfl_down(pk, off);
            if (o > pk) pk = o;
          }
          if (lane == 0)
            lds_tok[0] = (float)(0x7FFFu ^ (unsigned)((pk >> 17) & 0x7FFF));
        }
      }
      __syncthreads();
      if (wave < 8) {
        const int row = (wave & 3) * 512 + w * 2 + (wave >> 2);
        const float4* W4 =
            reinterpret_cast<const float4*>(p.dWhh0 + (size_t)row * 512);
        const float4* h4 = reinterpret_cast<const float4*>(lds_h0);
        float a = dot4(W4[lane * 2], h4[lane * 2]) +
                  dot4(W4[lane * 2 + 1], h4[lane * 2 + 1]);
        a = wred(a);
        if (lane == 0) lds_g[wave] = a;
      }
      __syncthreads();
      if (tid < 2) {
        const float tok = lds_tok[0];
        const int uu = w * 2 + tid;
        float gv[4];
#pragma unroll
        for (int g = 0; g < 4; ++g) {
          const int rg = g * 512 + uu;
          gv[g] = lds_g[tid * 4 + g] + p.dWih0[rg] * tok + p.db0[rg];
        }
        const float c2 = sigmf(gv[1]) * c0d + sigmf(gv[0]) * tanhf(gv[2]);
        c0d = c2;
        pub_write(p.h0d, ((t + 1) & 1) * 512 + uu, (unsigned)(t + 2),
                  sigmf(gv[3]) * tanhf(c2));
      }
    }
    // ---- D1: poll h0d slot (t+1)&1 (tag t+2) + h1d slot t&1 (tag t+1) ----
    {
      if (wave < 8)
        poll_stage(p.h0d + ((t + 1) & 1) * 512, (unsigned)(t + 2), lds_h0,
                   wave, lane);
      else
        poll_stage(p.h1d + (t & 1) * 512, (unsigned)(t + 1), lds_h1,
                   wave - 8, lane);
      __syncthreads();
      if (wave < 8) {
        const int row = (wave & 3) * 512 + w * 2 + (wave >> 2);
        const float4* Wa =
            reinterpret_cast<const float4*>(p.dWih1 + (size_t)row * 512);
        const float4* Wb =
            reinterpret_cast<const float4*>(p.dWhh1 + (size_t)row * 512);
        const float4* h4a = reinterpret_cast<const float4*>(lds_h0);
        const float4* h4b = reinterpret_cast<const float4*>(lds_h1);
        float a = (lane == 0) ? p.db1[row] : 0.f;
        a += dot4(Wa[lane * 2], h4a[lane * 2]) +
             dot4(Wa[lane * 2 + 1], h4a[lane * 2 + 1]);
        a += dot4(Wb[lane * 2], h4b[lane * 2]) +
             dot4(Wb[lane * 2 + 1], h4b[lane * 2 + 1]);
        a = wred(a);
        if (lane == 0) lds_g[wave] = a;
      }
      __syncthreads();
      if (tid < 2) {
        const int uu = w * 2 + tid;
        const float gi = lds_g[tid * 4 + 0];
        const float gf = lds_g[tid * 4 + 1];
        const float gg = lds_g[tid * 4 + 2];
        const float go = lds_g[tid * 4 + 3];
        const float c2 = sigmf(gf) * c1d + sigmf(gi) * tanhf(gg);
        c1d = c2;
        pub_write(p.h1d, ((t + 1) & 1) * 512 + uu, (unsigned)(t + 2),
                  sigmf(go) * tanhf(c2));
      }
    }
    // ---- FC: poll h1d slot (t+1)&1 (tag t+2); logits + tagged candidate ----
    {
      if (wave < 8)
        poll_stage(p.h1d + ((t + 1) & 1) * 512, (unsigned)(t + 2), lds_h0,
                   wave, lane);
      __syncthreads();
      const float4* h4 = reinterpret_cast<const float4*>(lds_h0);
      const float4 ha = h4[lane * 2], hb = h4[lane * 2 + 1];
      float* orow = p.out + (size_t)(t + 1) * kV;
      const unsigned tagout = (unsigned)(t + 1);
      unsigned long long best = 0;
      const int rb = w * 125 + kLdsRows + wave * 4;
#define FCR(i)                                                                \
  {                                                                           \
    const int row = rb + i;                                                   \
    float a = (lane == 0) ? bi##i : 0.f;                                      \
    a += dot4(Ra##i, ha) + dot4(Rb##i, hb);                                   \
    a = wred(a);                                                              \
    if (lane == 0) {                                                          \
      orow[row] = a;                                                          \
      const unsigned long long pk2 = pack_cand(a, row, tagout);               \
      if (pk2 > best) best = pk2;                                             \
    }                                                                         \
  }
      FCR(0) FCR(1) FCR(2) FCR(3)
#undef FCR
      for (int rr = wave; rr < kLdsRows; rr += 16) {
        const int row = w * 125 + rr;
        const float4* lw = reinterpret_cast<const float4*>(lds_w + rr * 512);
        float a = (lane == 0) ? lds_b[rr] : 0.f;
        a += dot4(lw[lane * 2], ha) + dot4(lw[lane * 2 + 1], hb);
        a = wred(a);
        if (lane == 0) {
          orow[row] = a;
          const unsigned long long pk2 = pack_cand(a, row, tagout);
          if (pk2 > best) best = pk2;
        }
      }
      if (lane == 0) lds_pk[wave] = best;
      __syncthreads();
      if (tid == 0) {
        unsigned long long b2 = lds_pk[0];
#pragma unroll
        for (int k2 = 1; k2 < 16; ++k2)
          if (lds_pk[k2] > b2) b2 = lds_pk[k2];
        g_st64(&p.cand[w], b2);
      }
    }
  }

  // zero output row 0 (P0/epub scratch in d_out, if used, is dead by now)
  {
    const int idx = w * NTHR + tid;
    if (idx < kV) p.out[idx] = 0.f;
  }
}

extern "C" void kernel_launch(void* const* d_in, const int* in_sizes, int n_in,
                              void* d_out, int out_size, void* d_ws, size_t ws_size,
                              hipStream_t stream) {
  (void)in_sizes; (void)n_in; (void)out_size;
  SeqParams P;
  P.x     = (const int*)d_in[0];
  P.y     = (const int*)d_in[1];
  P.emb   = (const float*)d_in[2];
  P.eWih0 = (const float*)d_in[3];
  P.eWhh0 = (const float*)d_in[4];
  P.eb0   = (const float*)d_in[5];
  P.eWih1 = (const float*)d_in[6];
  P.eWhh1 = (const float*)d_in[7];
  P.eb1   = (const float*)d_in[8];
  P.efcW  = (const float*)d_in[9];
  P.efcb  = (const float*)d_in[10];
  P.dWih0 = (const float*)d_in[11];
  P.dWhh0 = (const float*)d_in[12];
  P.db0   = (const float*)d_in[13];
  P.dWih1 = (const float*)d_in[14];
  P.dWhh1 = (const float*)d_in[15];
  P.db1   = (const float*)d_in[16];
  P.dfcW  = (const float*)d_in[17];
  P.dfcb  = (const float*)d_in[18];
  P.out   = (float*)d_out;

  char* ws = (char*)d_ws;
  P.arrive = (unsigned*)ws;                           // 32KB
  P.go     = (unsigned*)(ws + 32768);                 // 32KB
  P.cand   = (unsigned long long*)(ws + 65536);       // 2KB
  P.h0d    = (unsigned long long*)(ws + 67584);       // 8KB
  P.h1d    = (unsigned long long*)(ws + 75776);       // 8KB -> ends 83968

  const size_t kP0B  = 8388608ull;                    // 2048*1024*4
  const size_t kEpB  = 4198400ull;                    // 1025*512*8
  const size_t bigo  = 131072ull;
  if (ws_size >= bigo + kP0B + 2 * kEpB) {
    P.P0  = (float*)(ws + bigo);
    P.h0e = (unsigned long long*)(ws + bigo + kP0B);
    P.h1e = (unsigned long long*)(ws + bigo + kP0B + kEpB);
  } else {
    // d_out fallback: bytes [0, 16.8MB) = rows 0..~131, all dead before the
    // decoder's FC writes them (FC(t) writes row t+1, and any FC requires all
    // WGs to have finished the encoder via the cand/pub dependence chain).
    char* ob = (char*)d_out;
    P.P0  = (float*)ob;
    P.h0e = (unsigned long long*)(ob + kP0B);
    P.h1e = (unsigned long long*)(ob + kP0B + kEpB);
  }

  // Allow >64KB dynamic LDS (idempotent; capture-safe).
  hipFuncSetAttribute(reinterpret_cast<const void*>(seq2seq_kernel),
                      hipFuncAttributeMaxDynamicSharedMemorySize,
                      (int)kSmemBytes);

  // Reset barrier flags + cand + decoder ring pubs every call (replay-safe;
  // all poll tags are >=1 so zeroed words never satisfy a poll).
  hipMemsetAsync(d_ws, 0, 86016, stream);

  void* args[] = { &P };
  hipLaunchCooperativeKernel(reinterpret_cast<void*>(seq2seq_kernel),
                             dim3(NWG), dim3(NTHR), args, kSmemBytes, stream);
}